// Round 9
// baseline (190.494 us; speedup 1.0000x reference)
//
#include <hip/hip_runtime.h>
#include <math.h>

#define BB 4
#define CC 256
#define HWN 4096
#define NTOK 16384                 // BB*HWN
#define SCQ 0.09016844136f         // (1/sqrt(256)) * log2(e)
#define NZERO (3 * NTOK + 64)      // den/nx/ny + 64 done-counters

typedef __attribute__((ext_vector_type(8))) short short8;
typedef __attribute__((ext_vector_type(4))) float f32x4;
typedef unsigned short ushort_t;

__device__ __forceinline__ ushort_t f2bf(float f) {
    unsigned int u = __float_as_uint(f);
    unsigned int r = (u + 0x7FFFu + ((u >> 16) & 1u)) >> 16;   // RNE
    return (ushort_t)r;
}
__device__ __forceinline__ unsigned int pack2(float a, float b) {
    return (unsigned int)f2bf(a) | ((unsigned int)f2bf(b) << 16);
}

// ---------------------------------------------------------------------------
// wconv: blocks 0-31 convert weights fp32->bf16 ([d][c] kept; Q pre-scaled by
// (1/sqrt C)*log2e). Blocks 32+ zero den/nx/ny + done-counters.
// ---------------------------------------------------------------------------
__global__ __launch_bounds__(256) void wconv_kernel(
    const float* __restrict__ q_w, const float* __restrict__ k_w,
    ushort_t* __restrict__ wq, ushort_t* __restrict__ wk,
    float* __restrict__ zbuf)
{
    int bid = blockIdx.x, t = threadIdx.x;
    if (bid < 32) {
        int i = (bid * 256 + t) * 8;
        float4 a = *(const float4*)&q_w[i];
        float4 b = *(const float4*)&q_w[i + 4];
        uint4 o;
        o.x = pack2(a.x * SCQ, a.y * SCQ); o.y = pack2(a.z * SCQ, a.w * SCQ);
        o.z = pack2(b.x * SCQ, b.y * SCQ); o.w = pack2(b.z * SCQ, b.w * SCQ);
        *(uint4*)&wq[i] = o;
        a = *(const float4*)&k_w[i];
        b = *(const float4*)&k_w[i + 4];
        o.x = pack2(a.x, a.y); o.y = pack2(a.z, a.w);
        o.z = pack2(b.x, b.y); o.w = pack2(b.z, b.w);
        *(uint4*)&wk[i] = o;
    } else {
        int base = (bid - 32) * 256 + t;
        if (base < NZERO) zbuf[base] = 0.f;
    }
}

// ---------------------------------------------------------------------------
// MFMA projection. Block = 32 tokens x all 256 d, grid 512 (2 blocks/CU).
// Phase 1: stage feature -> bf16 LDS token-major (feature read once chip-wide).
// Phase 2 (barrier-free): per wave 64 d, bf16 weight frags (L2-hot) with
// register prefetch, 32 MFMA per 16-d slice, ushort4 token-major stores.
// ---------------------------------------------------------------------------
__global__ __launch_bounds__(256, 2) void proj_kernel(
    const float* __restrict__ feature,
    const ushort_t* __restrict__ wq, const ushort_t* __restrict__ wk,
    const float* __restrict__ q_bias, const float* __restrict__ k_bias,
    ushort_t* __restrict__ qb, ushort_t* __restrict__ kb)
{
    int tt = blockIdx.x & 127;
    int b  = blockIdx.x >> 7;
    int tok0 = tt * 32;

    int t = threadIdx.x, w = t >> 6, lane = t & 63;
    int n16 = lane & 15, quad = lane >> 4;

    __shared__ float    lsA[64][34];    // [c-in-chunk][tok] fp32
    __shared__ ushort_t lsB[32][264];   // [tok][c 0..255] bf16

    const float* F = feature + (size_t)(b * CC) * HWN;

    int cl = t >> 2, tg = (t & 3) * 8;      // stage: 64 rows x 32 tok
    int tokw = t >> 3, c8 = (t & 7) * 8;    // transpose: 32 tok x 8c-groups

    for (int ch = 0; ch < 4; ch++) {
        const float* src = F + (size_t)(ch * 64 + cl) * HWN + tok0 + tg;
        float4 v0 = *(const float4*)src;
        float4 v1 = *(const float4*)(src + 4);
        *(float2*)&lsA[cl][tg]     = make_float2(v0.x, v0.y);
        *(float2*)&lsA[cl][tg + 2] = make_float2(v0.z, v0.w);
        *(float2*)&lsA[cl][tg + 4] = make_float2(v1.x, v1.y);
        *(float2*)&lsA[cl][tg + 6] = make_float2(v1.z, v1.w);
        __syncthreads();
        uint4 o;
        o.x = pack2(lsA[c8 + 0][tokw], lsA[c8 + 1][tokw]);
        o.y = pack2(lsA[c8 + 2][tokw], lsA[c8 + 3][tokw]);
        o.z = pack2(lsA[c8 + 4][tokw], lsA[c8 + 5][tokw]);
        o.w = pack2(lsA[c8 + 6][tokw], lsA[c8 + 7][tokw]);
        *(uint4*)&lsB[tokw][ch * 64 + c8] = o;
        __syncthreads();
    }

    int dw0 = w * 64;
    short8 aq[8], ak[8], aq2[8], ak2[8];
    #pragma unroll
    for (int kc = 0; kc < 8; kc++) {
        size_t off = (size_t)(dw0 + n16) * CC + kc * 32 + quad * 8;
        aq[kc] = *(const short8*)&wq[off];
        ak[kc] = *(const short8*)&wk[off];
    }

    #pragma unroll
    for (int dsub = 0; dsub < 4; dsub++) {
        int d0 = dw0 + dsub * 16;
        if (dsub < 3) {
            #pragma unroll
            for (int kc = 0; kc < 8; kc++) {
                size_t off = (size_t)(d0 + 16 + n16) * CC + kc * 32 + quad * 8;
                aq2[kc] = *(const short8*)&wq[off];
                ak2[kc] = *(const short8*)&wk[off];
            }
        }
        f32x4 accq[2], acck[2];
        #pragma unroll
        for (int i = 0; i < 2; i++) {
            accq[i] = (f32x4){0.f, 0.f, 0.f, 0.f};
            acck[i] = (f32x4){0.f, 0.f, 0.f, 0.f};
        }
        #pragma unroll
        for (int kc = 0; kc < 8; kc++) {
            #pragma unroll
            for (int tokt = 0; tokt < 2; tokt++) {
                short8 bf = *(const short8*)&lsB[tokt * 16 + n16][kc * 32 + quad * 8];
                accq[tokt] = __builtin_amdgcn_mfma_f32_16x16x32_bf16(aq[kc], bf, accq[tokt], 0, 0, 0);
                acck[tokt] = __builtin_amdgcn_mfma_f32_16x16x32_bf16(ak[kc], bf, acck[tokt], 0, 0, 0);
            }
        }
        float bqv[4], bkv[4];
        #pragma unroll
        for (int r = 0; r < 4; r++) {
            bqv[r] = q_bias[d0 + quad * 4 + r] * SCQ;
            bkv[r] = k_bias[d0 + quad * 4 + r];
        }
        #pragma unroll
        for (int tokt = 0; tokt < 2; tokt++) {
            size_t row = (size_t)(b * HWN + tok0 + tokt * 16 + n16) * CC + d0 + quad * 4;
            ushort4 oq, ok;
            oq.x = f2bf(accq[tokt][0] + bqv[0]); oq.y = f2bf(accq[tokt][1] + bqv[1]);
            oq.z = f2bf(accq[tokt][2] + bqv[2]); oq.w = f2bf(accq[tokt][3] + bqv[3]);
            ok.x = f2bf(acck[tokt][0] + bkv[0]); ok.y = f2bf(acck[tokt][1] + bkv[1]);
            ok.z = f2bf(acck[tokt][2] + bkv[2]); ok.w = f2bf(acck[tokt][3] + bkv[3]);
            *(ushort4*)&qb[row] = oq;
            *(ushort4*)&kb[row] = ok;
        }
        #pragma unroll
        for (int kc = 0; kc < 8; kc++) { aq[kc] = aq2[kc]; ak[kc] = ak2[kc]; }
    }
}

// ---------------------------------------------------------------------------
// Flash MFMA attention (R7 structure, 4 blocks/CU) + fused finalize.
// Block = (b, 256-q, 256-key range), 4 waves x 64 q-rows resident; grid 1024
// qt-fastest (16 consecutive blocks share a K-range -> L2 reuse).
// 32-key stages, double-buffered 2 x 16 KB XOR-swizzled LDS, one barrier per
// stage (stage k+1 issued right after the barrier, drains a full compute
// phase later). Q pre-scaled by (1/16)*log2e => p = exp2(acc). No-max
// softmax => key-split additively exact via atomics; last block per (b,qt)
// divides and writes out.
// ---------------------------------------------------------------------------
__global__ __launch_bounds__(256, 2) void attn_kernel(
    const ushort_t* __restrict__ qb, const ushort_t* __restrict__ kb,
    const float* __restrict__ flow,
    float* __restrict__ den_g, float* __restrict__ nx_g, float* __restrict__ ny_g,
    int* __restrict__ cnt_g, float* __restrict__ out)
{
    int id = blockIdx.x;
    int qt = id & 15; id >>= 4;
    int sr = id & 15; id >>= 4;
    int b = id;

    int t = threadIdx.x;
    int w = t >> 6, lane = t & 63;
    int n16 = lane & 15, quad = lane >> 4;

    int q0 = qt * 256 + w * 64;
    int s_beg = sr * 256;

    const ushort_t* Qb = qb + (size_t)b * HWN * CC;
    const ushort_t* Kb = kb + (size_t)b * HWN * CC;

    __shared__ __align__(16) ushort_t lk[2][8192];   // 2 x 16 KB swizzled K
    __shared__ float lflow[512];                      // 256 vx + 256 vy

    const float* fx = flow + (size_t)b * 2 * HWN;
    const float* fy = fx + HWN;
    lflow[t]       = fx[s_beg + t];
    lflow[t + 256] = fy[s_beg + t];

    short8 qf[4][8];
    #pragma unroll
    for (int tq = 0; tq < 4; tq++)
        #pragma unroll
        for (int c = 0; c < 8; c++)
            qf[tq][c] = *(const short8*)&Qb[(size_t)(q0 + tq * 16 + n16) * CC
                                            + c * 32 + quad * 8];

    // staging source offsets (XOR swizzle on 16B granules), loop-invariant
    int srcoff[4];
    #pragma unroll
    for (int i = 0; i < 4; i++) {
        int G = i * 256 + t;
        int r = G >> 5, j = G & 31;        // 32 rows x 32 granules
        srcoff[i] = (r * 32 + (j ^ r)) * 16;
    }
    int p16[8];
    #pragma unroll
    for (int c = 0; c < 8; c++)
        p16[c] = (((c * 4 + quad) ^ n16) & 31) * 16;

    float den[4][4], nxa[4][4], nya[4][4];
    #pragma unroll
    for (int tq = 0; tq < 4; tq++)
        #pragma unroll
        for (int r = 0; r < 4; r++) { den[tq][r] = 0.f; nxa[tq][r] = 0.f; nya[tq][r] = 0.f; }

    // prologue: stage tile 0 into buffer 0
    {
        const char* gsrc = (const char*)(Kb + (size_t)s_beg * CC);
        char* ldst = (char*)lk[0] + t * 16;
        #pragma unroll
        for (int i = 0; i < 4; i++)
            __builtin_amdgcn_global_load_lds(
                (const __attribute__((address_space(1))) unsigned int*)(gsrc + srcoff[i]),
                (__attribute__((address_space(3))) unsigned int*)(ldst + i * 4096),
                16, 0, 0);
    }

    for (int st = 0; st < 8; st++) {
        __syncthreads();   // buffer st&1 staged; prior reads of other buffer done
        if (st + 1 < 8) {
            const char* gsrc = (const char*)(Kb + (size_t)(s_beg + (st + 1) * 32) * CC);
            char* ldst = (char*)lk[(st + 1) & 1] + t * 16;
            #pragma unroll
            for (int i = 0; i < 4; i++)
                __builtin_amdgcn_global_load_lds(
                    (const __attribute__((address_space(1))) unsigned int*)(gsrc + srcoff[i]),
                    (__attribute__((address_space(3))) unsigned int*)(ldst + i * 4096),
                    16, 0, 0);
        }
        const char* base = (const char*)lk[st & 1];

        #pragma unroll
        for (int bt = 0; bt < 2; bt++) {
            int rbase = (bt * 16 + n16) * 512;
            int x16   = bt ? 256 : 0;
            f32x4 a0 = {0.f, 0.f, 0.f, 0.f};
            f32x4 a1 = {0.f, 0.f, 0.f, 0.f};
            f32x4 a2 = {0.f, 0.f, 0.f, 0.f};
            f32x4 a3 = {0.f, 0.f, 0.f, 0.f};
            #pragma unroll
            for (int c = 0; c < 8; c++) {
                short8 kf = *(const short8*)(base + rbase + (p16[c] ^ x16));
                a0 = __builtin_amdgcn_mfma_f32_16x16x32_bf16(qf[0][c], kf, a0, 0, 0, 0);
                a1 = __builtin_amdgcn_mfma_f32_16x16x32_bf16(qf[1][c], kf, a1, 0, 0, 0);
                a2 = __builtin_amdgcn_mfma_f32_16x16x32_bf16(qf[2][c], kf, a2, 0, 0, 0);
                a3 = __builtin_amdgcn_mfma_f32_16x16x32_bf16(qf[3][c], kf, a3, 0, 0, 0);
            }
            int sidx = st * 32 + bt * 16 + n16;
            float vx = lflow[sidx];
            float vy = lflow[256 + sidx];
            #pragma unroll
            for (int r = 0; r < 4; r++) {
                float p0 = exp2f(a0[r]);
                float p1 = exp2f(a1[r]);
                float p2 = exp2f(a2[r]);
                float p3 = exp2f(a3[r]);
                den[0][r] += p0; den[1][r] += p1; den[2][r] += p2; den[3][r] += p3;
                nxa[0][r] = fmaf(p0, vx, nxa[0][r]); nxa[1][r] = fmaf(p1, vx, nxa[1][r]);
                nxa[2][r] = fmaf(p2, vx, nxa[2][r]); nxa[3][r] = fmaf(p3, vx, nxa[3][r]);
                nya[0][r] = fmaf(p0, vy, nya[0][r]); nya[1][r] = fmaf(p1, vy, nya[1][r]);
                nya[2][r] = fmaf(p2, vy, nya[2][r]); nya[3][r] = fmaf(p3, vy, nya[3][r]);
            }
        }
    }

    #pragma unroll
    for (int tq = 0; tq < 4; tq++)
        #pragma unroll
        for (int r = 0; r < 4; r++) {
            #pragma unroll
            for (int off = 8; off >= 1; off >>= 1) {
                den[tq][r] += __shfl_down(den[tq][r], off, 16);
                nxa[tq][r] += __shfl_down(nxa[tq][r], off, 16);
                nya[tq][r] += __shfl_down(nya[tq][r], off, 16);
            }
        }
    if (n16 == 0) {
        #pragma unroll
        for (int tq = 0; tq < 4; tq++)
            #pragma unroll
            for (int r = 0; r < 4; r++) {
                int qrow = q0 + tq * 16 + quad * 4 + r;
                int gi = b * HWN + qrow;
                atomicAdd(&den_g[gi], den[tq][r]);
                atomicAdd(&nx_g[gi],  nxa[tq][r]);
                atomicAdd(&ny_g[gi],  nya[tq][r]);
            }
    }

    // ---- last-block finalize for this (b, qt) 256-q tile ----
    __shared__ int is_last;
    __syncthreads();                 // all waves' atomics issued & complete
    if (t == 0) {
        __threadfence();             // release partials to device scope
        int old = __hip_atomic_fetch_add(&cnt_g[b * 16 + qt], 1,
                                         __ATOMIC_ACQ_REL, __HIP_MEMORY_SCOPE_AGENT);
        is_last = (old == 15);
    }
    __syncthreads();
    if (is_last) {
        __threadfence();             // acquire: see all 16 blocks' partials
        int qrow = qt * 256 + t;     // 256 threads x 1 row
        int gi = b * HWN + qrow;
        float d = __hip_atomic_load(&den_g[gi], __ATOMIC_RELAXED, __HIP_MEMORY_SCOPE_AGENT);
        float x = __hip_atomic_load(&nx_g[gi],  __ATOMIC_RELAXED, __HIP_MEMORY_SCOPE_AGENT);
        float y = __hip_atomic_load(&ny_g[gi],  __ATOMIC_RELAXED, __HIP_MEMORY_SCOPE_AGENT);
        float inv = 1.0f / d;
        out[(size_t)b * 2 * HWN + qrow]       = x * inv;
        out[(size_t)b * 2 * HWN + HWN + qrow] = y * inv;
    }
}

extern "C" void kernel_launch(void* const* d_in, const int* in_sizes, int n_in,
                              void* d_out, int out_size, void* d_ws, size_t ws_size,
                              hipStream_t stream) {
    const float* feature = (const float*)d_in[0];
    const float* flow    = (const float*)d_in[1];
    const float* q_w     = (const float*)d_in[2];
    const float* q_b     = (const float*)d_in[3];
    const float* k_w     = (const float*)d_in[4];
    const float* k_b     = (const float*)d_in[5];
    float* out = (float*)d_out;

    ushort_t* qbuf = (ushort_t*)d_ws;                     // [NTOK][CC] bf16
    ushort_t* kbuf = qbuf + (size_t)NTOK * CC;            // [NTOK][CC] bf16
    ushort_t* wq   = kbuf + (size_t)NTOK * CC;            // [CC][CC] bf16
    ushort_t* wk   = wq + (size_t)CC * CC;
    float* den = (float*)(wk + (size_t)CC * CC);          // [NTOK]
    float* nx  = den + NTOK;
    float* ny  = nx + NTOK;
    int*   cnt = (int*)(ny + NTOK);                       // 64 counters

    wconv_kernel<<<256, 256, 0, stream>>>(q_w, k_w, wq, wk, den);  // + zeroing
    proj_kernel<<<512, 256, 0, stream>>>(feature, wq, wk, q_b, k_b, qbuf, kbuf);
    attn_kernel<<<1024, 256, 0, stream>>>(qbuf, kbuf, flow, den, nx, ny, cnt, out);
}

// Round 10
// 163.082 us; speedup vs baseline: 1.1681x; 1.1681x over previous
//
#include <hip/hip_runtime.h>
#include <math.h>

#define BB 4
#define CC 256
#define HWN 4096
#define NTOK 16384                 // BB*HWN
#define SCQ 0.09016844136f         // (1/sqrt(256)) * log2(e)

typedef __attribute__((ext_vector_type(8))) short short8;
typedef __attribute__((ext_vector_type(4))) float f32x4;
typedef unsigned short ushort_t;

__device__ __forceinline__ ushort_t f2bf(float f) {
    unsigned int u = __float_as_uint(f);
    unsigned int r = (u + 0x7FFFu + ((u >> 16) & 1u)) >> 16;   // RNE
    return (ushort_t)r;
}
__device__ __forceinline__ unsigned int pack2(float a, float b) {
    return (unsigned int)f2bf(a) | ((unsigned int)f2bf(b) << 16);
}
__device__ __forceinline__ float bf2f(ushort_t u) {
    return __uint_as_float(((unsigned int)u) << 16);
}

// ---------------------------------------------------------------------------
// prep: P[b_][a] = SCQ * sum_c W_k[c][b_] * W_q[c][a]  (bf16, row-major d_out=b_)
//       w1[b_]   = SCQ * sum_c W_k[c][b_] * b_q[c]
// Softmax row-constants (b_k-side terms) cancel and are dropped.
// Also zeroes den/nx/ny. Grid 256 (one 16x16 P-tile per block).
// ---------------------------------------------------------------------------
__global__ __launch_bounds__(256) void prep_kernel(
    const float* __restrict__ q_w, const float* __restrict__ k_w,
    const float* __restrict__ q_bias,
    ushort_t* __restrict__ P, float* __restrict__ w1, float* __restrict__ zbuf)
{
    int bid = blockIdx.x, t = threadIdx.x;
    int gid = bid * 256 + t;
    if (gid < 3 * NTOK) zbuf[gid] = 0.f;

    int ta = bid & 15, tb = bid >> 4;
    int a_ = ta * 16 + (t & 15);
    int b_ = tb * 16 + (t >> 4);

    float acc0 = 0.f, acc1 = 0.f, acc2 = 0.f, acc3 = 0.f;
    for (int c = 0; c < CC; c += 4) {
        acc0 = fmaf(k_w[(c + 0) * CC + b_], q_w[(c + 0) * CC + a_], acc0);
        acc1 = fmaf(k_w[(c + 1) * CC + b_], q_w[(c + 1) * CC + a_], acc1);
        acc2 = fmaf(k_w[(c + 2) * CC + b_], q_w[(c + 2) * CC + a_], acc2);
        acc3 = fmaf(k_w[(c + 3) * CC + b_], q_w[(c + 3) * CC + a_], acc3);
    }
    P[b_ * CC + a_] = f2bf((acc0 + acc1 + acc2 + acc3) * SCQ);

    if (ta == 0) {
        int cseg = (t & 15) * 16;
        float p = 0.f;
        #pragma unroll
        for (int cc = 0; cc < 16; cc++)
            p = fmaf(k_w[(cseg + cc) * CC + b_], q_bias[cseg + cc], p);
        #pragma unroll
        for (int off = 8; off >= 1; off >>= 1)
            p += __shfl_down(p, off, 16);
        if ((t & 15) == 0) w1[b_] = p * SCQ;
    }
}

// ---------------------------------------------------------------------------
// tproj. Block = 32 tokens, grid 512. Phase 1: stage feature -> bf16 LDS
// token-major; each chunk's bf16 tile is ALSO streamed to ft (raw-token
// B-operand — no K projection needed anymore). Phase 2: tv_j = w1 . f_j per
// token. Phase 3 (barrier-free): f~ = P f via MFMA (A = P rows, L2-hot,
// register-prefetched), ushort4 token-major stores, no bias.
// ---------------------------------------------------------------------------
__global__ __launch_bounds__(256, 2) void tproj_kernel(
    const float* __restrict__ feature,
    const ushort_t* __restrict__ P, const float* __restrict__ w1,
    ushort_t* __restrict__ fq, ushort_t* __restrict__ ft,
    float* __restrict__ tv)
{
    int tt = blockIdx.x & 127;
    int b  = blockIdx.x >> 7;
    int tok0 = tt * 32;

    int t = threadIdx.x, w = t >> 6, lane = t & 63;
    int n16 = lane & 15, quad = lane >> 4;

    __shared__ float    lsA[64][34];    // [c-in-chunk][tok] fp32
    __shared__ ushort_t lsB[32][264];   // [tok][c 0..255] bf16

    const float* F = feature + (size_t)(b * CC) * HWN;

    int cl = t >> 2, tg = (t & 3) * 8;      // stage: 64 rows x 32 tok
    int tokw = t >> 3, c8 = (t & 7) * 8;    // transpose: 32 tok x 8c-groups

    for (int ch = 0; ch < 4; ch++) {
        const float* src = F + (size_t)(ch * 64 + cl) * HWN + tok0 + tg;
        float4 v0 = *(const float4*)src;
        float4 v1 = *(const float4*)(src + 4);
        *(float2*)&lsA[cl][tg]     = make_float2(v0.x, v0.y);
        *(float2*)&lsA[cl][tg + 2] = make_float2(v0.z, v0.w);
        *(float2*)&lsA[cl][tg + 4] = make_float2(v1.x, v1.y);
        *(float2*)&lsA[cl][tg + 6] = make_float2(v1.z, v1.w);
        __syncthreads();
        uint4 o;
        o.x = pack2(lsA[c8 + 0][tokw], lsA[c8 + 1][tokw]);
        o.y = pack2(lsA[c8 + 2][tokw], lsA[c8 + 3][tokw]);
        o.z = pack2(lsA[c8 + 4][tokw], lsA[c8 + 5][tokw]);
        o.w = pack2(lsA[c8 + 6][tokw], lsA[c8 + 7][tokw]);
        *(uint4*)&lsB[tokw][ch * 64 + c8] = o;
        // stream the raw bf16 token tile straight out (B-side of scores)
        *(uint4*)&ft[(size_t)(b * HWN + tok0 + tokw) * CC + ch * 64 + c8] = o;
        __syncthreads();
    }

    // per-key scalar: tv_j = w1 . f_j
    {
        int tok = t >> 3, cs = (t & 7) * 32;
        float tp = 0.f;
        #pragma unroll
        for (int cc = 0; cc < 32; cc++)
            tp = fmaf(bf2f(lsB[tok][cs + cc]), w1[cs + cc], tp);
        #pragma unroll
        for (int off = 4; off >= 1; off >>= 1)
            tp += __shfl_xor(tp, off, 8);
        if ((t & 7) == 0) tv[b * HWN + tok0 + tok] = tp;
    }

    int dw0 = w * 64;
    short8 ap[8], ap2[8];
    #pragma unroll
    for (int kc = 0; kc < 8; kc++)
        ap[kc] = *(const short8*)&P[(size_t)(dw0 + n16) * CC + kc * 32 + quad * 8];

    #pragma unroll
    for (int dsub = 0; dsub < 4; dsub++) {
        int d0 = dw0 + dsub * 16;
        if (dsub < 3) {
            #pragma unroll
            for (int kc = 0; kc < 8; kc++)
                ap2[kc] = *(const short8*)&P[(size_t)(d0 + 16 + n16) * CC + kc * 32 + quad * 8];
        }
        f32x4 acc[2];
        acc[0] = (f32x4){0.f, 0.f, 0.f, 0.f};
        acc[1] = (f32x4){0.f, 0.f, 0.f, 0.f};
        #pragma unroll
        for (int kc = 0; kc < 8; kc++) {
            #pragma unroll
            for (int tokt = 0; tokt < 2; tokt++) {
                short8 bf = *(const short8*)&lsB[tokt * 16 + n16][kc * 32 + quad * 8];
                acc[tokt] = __builtin_amdgcn_mfma_f32_16x16x32_bf16(ap[kc], bf, acc[tokt], 0, 0, 0);
            }
        }
        #pragma unroll
        for (int tokt = 0; tokt < 2; tokt++) {
            size_t row = (size_t)(b * HWN + tok0 + tokt * 16 + n16) * CC + d0 + quad * 4;
            ushort4 oq;
            oq.x = f2bf(acc[tokt][0]); oq.y = f2bf(acc[tokt][1]);
            oq.z = f2bf(acc[tokt][2]); oq.w = f2bf(acc[tokt][3]);
            *(ushort4*)&fq[row] = oq;
        }
        #pragma unroll
        for (int kc = 0; kc < 8; kc++) ap[kc] = ap2[kc];
    }
}

// ---------------------------------------------------------------------------
// Flash MFMA attention (R7-exact structure, proven 56.4 us).
// Block = (b, 256-q, 512-key range), 4 waves x 64 q-rows; grid 512 qt-fastest.
// 32-key stages, double-buffered 2 x 16 KB XOR-swizzled LDS, one barrier per
// stage. A = f~ (P-projected tokens), B = raw bf16 tokens;
// p = exp2(f~_i . f_j + tv_j). No-max softmax => key-split exact via atomics.
// ---------------------------------------------------------------------------
__global__ __launch_bounds__(256, 2) void attn_kernel(
    const ushort_t* __restrict__ fq, const ushort_t* __restrict__ ft,
    const float* __restrict__ flow, const float* __restrict__ tv,
    float* __restrict__ den_g, float* __restrict__ nx_g, float* __restrict__ ny_g)
{
    int id = blockIdx.x;
    int qt = id & 15; id >>= 4;
    int sr = id & 7;  id >>= 3;
    int b = id;

    int t = threadIdx.x;
    int w = t >> 6, lane = t & 63;
    int n16 = lane & 15, quad = lane >> 4;

    int q0 = qt * 256 + w * 64;
    int s_beg = sr * 512;

    const ushort_t* Qb = fq + (size_t)b * HWN * CC;
    const ushort_t* Kb = ft + (size_t)b * HWN * CC;

    __shared__ __align__(16) ushort_t lk[2][8192];   // 2 x 16 KB swizzled K
    __shared__ float lflow[1536];                     // 512 vx + 512 vy + 512 tv

    const float* fx = flow + (size_t)b * 2 * HWN;
    const float* fy = fx + HWN;
    lflow[t]        = fx[s_beg + t];
    lflow[t + 256]  = fx[s_beg + t + 256];
    lflow[t + 512]  = fy[s_beg + t];
    lflow[t + 768]  = fy[s_beg + t + 256];
    lflow[t + 1024] = tv[b * HWN + s_beg + t];
    lflow[t + 1280] = tv[b * HWN + s_beg + t + 256];

    short8 qf[4][8];
    #pragma unroll
    for (int tq = 0; tq < 4; tq++)
        #pragma unroll
        for (int c = 0; c < 8; c++)
            qf[tq][c] = *(const short8*)&Qb[(size_t)(q0 + tq * 16 + n16) * CC
                                            + c * 32 + quad * 8];

    int srcoff[4];
    #pragma unroll
    for (int i = 0; i < 4; i++) {
        int G = i * 256 + t;
        int r = G >> 5, j = G & 31;        // 32 rows x 32 granules
        srcoff[i] = (r * 32 + (j ^ r)) * 16;
    }
    int p16[8];
    #pragma unroll
    for (int c = 0; c < 8; c++)
        p16[c] = (((c * 4 + quad) ^ n16) & 31) * 16;

    float den[4][4], nxa[4][4], nya[4][4];
    #pragma unroll
    for (int tq = 0; tq < 4; tq++)
        #pragma unroll
        for (int r = 0; r < 4; r++) { den[tq][r] = 0.f; nxa[tq][r] = 0.f; nya[tq][r] = 0.f; }

    {
        const char* gsrc = (const char*)(Kb + (size_t)s_beg * CC);
        char* ldst = (char*)lk[0] + t * 16;
        #pragma unroll
        for (int i = 0; i < 4; i++)
            __builtin_amdgcn_global_load_lds(
                (const __attribute__((address_space(1))) unsigned int*)(gsrc + srcoff[i]),
                (__attribute__((address_space(3))) unsigned int*)(ldst + i * 4096),
                16, 0, 0);
    }

    for (int st = 0; st < 16; st++) {
        __syncthreads();
        if (st + 1 < 16) {
            const char* gsrc = (const char*)(Kb + (size_t)(s_beg + (st + 1) * 32) * CC);
            char* ldst = (char*)lk[(st + 1) & 1] + t * 16;
            #pragma unroll
            for (int i = 0; i < 4; i++)
                __builtin_amdgcn_global_load_lds(
                    (const __attribute__((address_space(1))) unsigned int*)(gsrc + srcoff[i]),
                    (__attribute__((address_space(3))) unsigned int*)(ldst + i * 4096),
                    16, 0, 0);
        }
        const char* base = (const char*)lk[st & 1];

        #pragma unroll
        for (int bt = 0; bt < 2; bt++) {
            int rbase = (bt * 16 + n16) * 512;
            int x16   = bt ? 256 : 0;
            f32x4 a0 = {0.f, 0.f, 0.f, 0.f};
            f32x4 a1 = {0.f, 0.f, 0.f, 0.f};
            f32x4 a2 = {0.f, 0.f, 0.f, 0.f};
            f32x4 a3 = {0.f, 0.f, 0.f, 0.f};
            #pragma unroll
            for (int c = 0; c < 8; c++) {
                short8 kf = *(const short8*)(base + rbase + (p16[c] ^ x16));
                a0 = __builtin_amdgcn_mfma_f32_16x16x32_bf16(qf[0][c], kf, a0, 0, 0, 0);
                a1 = __builtin_amdgcn_mfma_f32_16x16x32_bf16(qf[1][c], kf, a1, 0, 0, 0);
                a2 = __builtin_amdgcn_mfma_f32_16x16x32_bf16(qf[2][c], kf, a2, 0, 0, 0);
                a3 = __builtin_amdgcn_mfma_f32_16x16x32_bf16(qf[3][c], kf, a3, 0, 0, 0);
            }
            int sidx = st * 32 + bt * 16 + n16;
            float vx  = lflow[sidx];
            float vy  = lflow[512 + sidx];
            float tvv = lflow[1024 + sidx];
            #pragma unroll
            for (int r = 0; r < 4; r++) {
                float p0 = exp2f(a0[r] + tvv);
                float p1 = exp2f(a1[r] + tvv);
                float p2 = exp2f(a2[r] + tvv);
                float p3 = exp2f(a3[r] + tvv);
                den[0][r] += p0; den[1][r] += p1; den[2][r] += p2; den[3][r] += p3;
                nxa[0][r] = fmaf(p0, vx, nxa[0][r]); nxa[1][r] = fmaf(p1, vx, nxa[1][r]);
                nxa[2][r] = fmaf(p2, vx, nxa[2][r]); nxa[3][r] = fmaf(p3, vx, nxa[3][r]);
                nya[0][r] = fmaf(p0, vy, nya[0][r]); nya[1][r] = fmaf(p1, vy, nya[1][r]);
                nya[2][r] = fmaf(p2, vy, nya[2][r]); nya[3][r] = fmaf(p3, vy, nya[3][r]);
            }
        }
    }

    #pragma unroll
    for (int tq = 0; tq < 4; tq++)
        #pragma unroll
        for (int r = 0; r < 4; r++) {
            #pragma unroll
            for (int off = 8; off >= 1; off >>= 1) {
                den[tq][r] += __shfl_down(den[tq][r], off, 16);
                nxa[tq][r] += __shfl_down(nxa[tq][r], off, 16);
                nya[tq][r] += __shfl_down(nya[tq][r], off, 16);
            }
        }
    if (n16 == 0) {
        #pragma unroll
        for (int tq = 0; tq < 4; tq++)
            #pragma unroll
            for (int r = 0; r < 4; r++) {
                int qrow = q0 + tq * 16 + quad * 4 + r;
                int gi = b * HWN + qrow;
                atomicAdd(&den_g[gi], den[tq][r]);
                atomicAdd(&nx_g[gi],  nxa[tq][r]);
                atomicAdd(&ny_g[gi],  nya[tq][r]);
            }
    }
}

// ---------------------------------------------------------------------------
__global__ __launch_bounds__(256) void finalize_kernel(
    const float* __restrict__ den_g, const float* __restrict__ nx_g,
    const float* __restrict__ ny_g, float* __restrict__ out)
{
    int idx = blockIdx.x * 256 + threadIdx.x;  // b*HW + n
    int b = idx >> 12, n = idx & 4095;
    float inv = 1.0f / den_g[idx];
    out[(size_t)b * 2 * HWN + n]       = nx_g[idx] * inv;
    out[(size_t)b * 2 * HWN + HWN + n] = ny_g[idx] * inv;
}

extern "C" void kernel_launch(void* const* d_in, const int* in_sizes, int n_in,
                              void* d_out, int out_size, void* d_ws, size_t ws_size,
                              hipStream_t stream) {
    const float* feature = (const float*)d_in[0];
    const float* flow    = (const float*)d_in[1];
    const float* q_w     = (const float*)d_in[2];
    const float* q_b     = (const float*)d_in[3];
    const float* k_w     = (const float*)d_in[4];
    // k_b unused: b_k-side softmax terms cancel (row constants)
    float* out = (float*)d_out;

    ushort_t* fq = (ushort_t*)d_ws;                       // [NTOK][CC] bf16
    ushort_t* ft = fq + (size_t)NTOK * CC;                // [NTOK][CC] bf16
    ushort_t* P  = ft + (size_t)NTOK * CC;                // [CC][CC] bf16
    float* w1  = (float*)(P + (size_t)CC * CC);           // [CC]
    float* tvb = w1 + CC;                                 // [NTOK]
    float* den = tvb + NTOK;                              // [NTOK]
    float* nx  = den + NTOK;
    float* ny  = nx + NTOK;

    prep_kernel<<<256, 256, 0, stream>>>(q_w, k_w, q_b, P, w1, den);  // + zeroing
    tproj_kernel<<<512, 256, 0, stream>>>(feature, P, w1, fq, ft, tvb);
    attn_kernel<<<512, 256, 0, stream>>>(fq, ft, flow, tvb, den, nx, ny);
    finalize_kernel<<<64, 256, 0, stream>>>(den, nx, ny, out);
}